// Round 6
// baseline (610.547 us; speedup 1.0000x reference)
//
#include <hip/hip_runtime.h>

// MFMA fragment types (gfx950): 16x16x32 f16 -> A/B = 8 x _Float16, C/D = 4 x float
typedef _Float16 half8 __attribute__((ext_vector_type(8)));
typedef __fp16 fp16x2 __attribute__((ext_vector_type(2)));   // cvt_pkrtz return type
typedef float floatx4 __attribute__((ext_vector_type(4)));
typedef unsigned int uintx4 __attribute__((ext_vector_type(4)));

#define MSGW 64      // message width
#define DEG 8        // fixed in-degree; triplets per edge

// log2-domain softplus: u = max(z',0) + log2(1+2^-|z'|) where z' = log2e*z.
// Then ln2*u = softplus(z). Scale factors folded into staged weights:
//   W1,b1 *= log2e  (so layer-1 acc is z1')
//   W2 unscaled, b2 *= log2e  (ln2*u1 @ W2 * log2e keeps the domain: ln2*log2e = 1)
//   W3 *= ln2 (recovers h2 @ W3 from u2)
__device__ __forceinline__ float softplus_l2(float z) {
    float e = __builtin_amdgcn_exp2f(-__builtin_fabsf(z));   // 2^-|z'|
    return fmaxf(z, 0.0f) + __builtin_amdgcn_logf(1.0f + e); // v_log_f32 = log2
}

__device__ __forceinline__ half8 cvt8(const float* p) {
    float4 x = *(const float4*)p;
    float4 y = *(const float4*)(p + 4);
    uintx4 w;
    w.x = __builtin_bit_cast(unsigned int, __builtin_amdgcn_cvt_pkrtz(x.x, x.y));
    w.y = __builtin_bit_cast(unsigned int, __builtin_amdgcn_cvt_pkrtz(x.z, x.w));
    w.z = __builtin_bit_cast(unsigned int, __builtin_amdgcn_cvt_pkrtz(y.x, y.y));
    w.w = __builtin_bit_cast(unsigned int, __builtin_amdgcn_cvt_pkrtz(y.z, y.w));
    return __builtin_bit_cast(half8, w);
}

// TRANSPOSED formulation: compute h^T = W^T @ X so that hidden units live on
// MFMA rows and triplets on columns. Lane (q = lane>>4, s = lane&15):
//   A-frag: A[m=s][k=q*8+j]    B-frag: B[k=q*8+j][n=s]    C/D: D[q*4+rr][s]
// The gathered message fragment (8 consecutive k of triplet s per lane) is
// simultaneously a valid B-fragment -> same gather as the untransposed form.
// Layer-2's K-order is OURS to choose (MFMA sums K in any order; we permute
// W2's staged A-fragment to match): k-slot (ks2,q,j) <- hidden
//   h = (ks2*2 + (j>>2))*16 + q*4 + (j&3)
// which makes each lane's layer-1 outputs exactly its own layer-2 B-fragment:
// ZERO inter-layer shuffles/LDS. Epilogue: each lane holds 16 hidden of its
// own triplet -> 2 shuffles (m reduce) + 3 shuffles (edge pool).
// NOTE: the inter-layer pack MUST be pure vector bit_casts — a union here
// defeats SROA and sends everything to scratch (R5: 500us, 1.9GB HBM).
__global__ __launch_bounds__(256, 6)
void triplet_mlp_kernel(const float* __restrict__ messages,
                        const float* __restrict__ r2,
                        const float* __restrict__ W1, const float* __restrict__ b1,
                        const float* __restrict__ W2, const float* __restrict__ b2,
                        const float* __restrict__ W3, const float* __restrict__ b3,
                        const int* __restrict__ idx_kj,
                        float* __restrict__ sacc, float* __restrict__ cnt,
                        int nChunks)
{
    __shared__ __align__(16) _Float16 lw1x[16 * 512];  // frag (nt*4+ks), lane-order, *log2e
    __shared__ __align__(16) _Float16 lw2x[8 * 512];   // frag (nt2*2+ks2), K-permuted
    __shared__ __align__(16) float lb1[64];            // *log2e
    __shared__ __align__(16) float lb2[64];            // *log2e
    __shared__ __align__(16) float lw3f[64];           // *ln2

    const float LOG2E = 1.44269504088896340736f;
    const float LN2   = 0.69314718055994530942f;

    const int tid = threadIdx.x;
    for (int i = tid; i < 128 * 64; i += 256) {
        int k = i >> 6, n = i & 63;          // W1[k][n] row-major
        int ks = k >> 5, q = (k >> 3) & 3, j = k & 7;
        int nt = n >> 4, s = n & 15;
        lw1x[(nt * 4 + ks) * 512 + (q * 16 + s) * 8 + j] = (_Float16)(W1[i] * LOG2E);
    }
    for (int i = tid; i < 64 * 64; i += 256) {
        int h = i >> 6, n = i & 63;          // W2[h][n] row-major
        int ks2 = h >> 5, q = (h >> 2) & 3, j = ((h >> 4) & 1) * 4 + (h & 3);
        int nt2 = n >> 4, s = n & 15;
        lw2x[(nt2 * 2 + ks2) * 512 + (q * 16 + s) * 8 + j] = (_Float16)W2[i];
    }
    if (tid < 64) {
        lb1[tid] = b1[tid] * LOG2E;
        lb2[tid] = b2[tid] * LOG2E;
        lw3f[tid] = W3[tid] * LN2;
    }
    __syncthreads();

    const int lane = tid & 63;
    const int s = lane & 15;                 // triplet column within the 16-wide tile
    const int q = lane >> 4;                 // quad
    const float b3v = b3[0];
    const int T = nChunks * 64;
    const int stride = gridDim.x * 64;

    int t = blockIdx.x * 64 + (tid >> 6) * 16 + s;   // this lane's triplet
    int kj = (t < T) ? idx_kj[t] : 0;

    for (int chunk = blockIdx.x; chunk < nChunks; chunk += gridDim.x) {
        // rotating index prefetch
        const int t_next = t + stride;
        const int kj_next = idx_kj[(t_next < T) ? t_next : 0];

        const int ji = t >> 3;                   // idx_ji[t] structural
        const int jn = kj >> 3;                  // idx_j[t] structural (uniform per edge)

        // gather B-fragments: k 0..63 = messages[kj], 64..127 = messages[ji]
        const float* mk = messages + (size_t)kj * MSGW + q * 8;
        const float* mj = messages + (size_t)ji * MSGW + q * 8;
        half8 bfr[4];
        bfr[0] = cvt8(mk);
        bfr[1] = cvt8(mk + 32);
        bfr[2] = cvt8(mj);
        bfr[3] = cvt8(mj + 32);

        const float rk = r2[(size_t)kj * 2 + (q & 1)];   // only this quad's component

        // ---- layer 1 (transposed): z1'^T[64x16] = (log2e*W1)^T @ X ----
        floatx4 acc[4];
#pragma unroll
        for (int nt = 0; nt < 4; ++nt)
            acc[nt] = *(const floatx4*)&lb1[nt * 16 + q * 4];   // broadcast b128
#pragma unroll
        for (int ks = 0; ks < 4; ++ks)
#pragma unroll
            for (int nt = 0; nt < 4; ++nt) {
                half8 af = *(const half8*)&lw1x[(nt * 4 + ks) * 512 + lane * 8];
                acc[nt] = __builtin_amdgcn_mfma_f32_16x16x32_f16(af, bfr[ks], acc[nt], 0, 0, 0);
            }

        // softplus (log2-domain) + pack: vector bit_casts only (no union!)
        uintx4 w0, w1;
        w0.x = __builtin_bit_cast(unsigned int,
                __builtin_amdgcn_cvt_pkrtz(softplus_l2(acc[0][0]), softplus_l2(acc[0][1])));
        w0.y = __builtin_bit_cast(unsigned int,
                __builtin_amdgcn_cvt_pkrtz(softplus_l2(acc[0][2]), softplus_l2(acc[0][3])));
        w0.z = __builtin_bit_cast(unsigned int,
                __builtin_amdgcn_cvt_pkrtz(softplus_l2(acc[1][0]), softplus_l2(acc[1][1])));
        w0.w = __builtin_bit_cast(unsigned int,
                __builtin_amdgcn_cvt_pkrtz(softplus_l2(acc[1][2]), softplus_l2(acc[1][3])));
        w1.x = __builtin_bit_cast(unsigned int,
                __builtin_amdgcn_cvt_pkrtz(softplus_l2(acc[2][0]), softplus_l2(acc[2][1])));
        w1.y = __builtin_bit_cast(unsigned int,
                __builtin_amdgcn_cvt_pkrtz(softplus_l2(acc[2][2]), softplus_l2(acc[2][3])));
        w1.z = __builtin_bit_cast(unsigned int,
                __builtin_amdgcn_cvt_pkrtz(softplus_l2(acc[3][0]), softplus_l2(acc[3][1])));
        w1.w = __builtin_bit_cast(unsigned int,
                __builtin_amdgcn_cvt_pkrtz(softplus_l2(acc[3][2]), softplus_l2(acc[3][3])));
        half8 u1a = __builtin_bit_cast(half8, w0);   // layer-2 B-frag, ks2=0
        half8 u1b = __builtin_bit_cast(half8, w1);   // layer-2 B-frag, ks2=1

        // ---- layer 2 (transposed, K-permuted): z2'^T = W2^T @ u1^T ----
        floatx4 acc2[4];
#pragma unroll
        for (int nt2 = 0; nt2 < 4; ++nt2)
            acc2[nt2] = *(const floatx4*)&lb2[nt2 * 16 + q * 4];
#pragma unroll
        for (int nt2 = 0; nt2 < 4; ++nt2) {
            half8 af0 = *(const half8*)&lw2x[(nt2 * 2 + 0) * 512 + lane * 8];
            acc2[nt2] = __builtin_amdgcn_mfma_f32_16x16x32_f16(af0, u1a, acc2[nt2], 0, 0, 0);
            half8 af1 = *(const half8*)&lw2x[(nt2 * 2 + 1) * 512 + lane * 8];
            acc2[nt2] = __builtin_amdgcn_mfma_f32_16x16x32_f16(af1, u1b, acc2[nt2], 0, 0, 0);
        }

        // ---- layer 3: m[s] = sum_h softplus(z2)[h] * W3[h] + b3 ----
        float msum = 0.0f;
#pragma unroll
        for (int nt2 = 0; nt2 < 4; ++nt2) {
            floatx4 w3q = *(const floatx4*)&lw3f[nt2 * 16 + q * 4];
#pragma unroll
            for (int rr = 0; rr < 4; ++rr)
                msum += softplus_l2(acc2[nt2][rr]) * w3q[rr];
        }
        msum += __shfl_xor(msum, 16, 64);     // reduce over the 4 q-lanes of column s
        msum += __shfl_xor(msum, 32, 64);
        const float m = msum + b3v;

        // edge pooling: v[bb] = sum_{k in edge} m_k * rk_k[bb], bb = q&1
        float c = m * rk;
        c += __shfl_xor(c, 1, 16);
        c += __shfl_xor(c, 2, 16);
        c += __shfl_xor(c, 4, 16);            // lanes s=0/s=8 hold the two edges' sums

        if ((s & 7) == 0) {
            const int aa = q >> 1, bb = q & 1;           // dyad: rj[aa]*v[bb]
            const float rj = r2[(size_t)ji * 2 + aa];    // ji uniform within edge
            atomicAdd(&sacc[(size_t)jn * 4 + aa * 2 + bb], rj * c);
            if (q == 0) atomicAdd(&cnt[jn], 8.0f);       // 8 triplets pooled per edge
        }

        t = t_next;
        kj = kj_next;
    }
}

__global__ void finalize_kernel(const float* __restrict__ sacc, const float* __restrict__ cnt,
                                float* __restrict__ out, int n4) {
    int i = blockIdx.x * 256 + threadIdx.x;
    if (i < n4) {
        float c = cnt[i >> 2];
        out[i] = sacc[i] / fmaxf(c, 1.0f);
    }
}

extern "C" void kernel_launch(void* const* d_in, const int* in_sizes, int n_in,
                              void* d_out, int out_size, void* d_ws, size_t ws_size,
                              hipStream_t stream) {
    const float* messages = (const float*)d_in[0];
    const float* r2       = (const float*)d_in[1];
    const float* W1       = (const float*)d_in[2];
    const float* b1       = (const float*)d_in[3];
    const float* W2       = (const float*)d_in[4];
    const float* b2       = (const float*)d_in[5];
    const float* W3       = (const float*)d_in[6];
    const float* b3       = (const float*)d_in[7];
    const int* idx_kj     = (const int*)d_in[8];

    const int T = in_sizes[8];          // 1,280,000 triplets
    const int N = out_size / 4;         // 20,000 nodes
    float* sacc = (float*)d_ws;         // [N*4] pooled sums
    float* cntp = sacc + (size_t)N * 4; // [N] counts

    (void)hipMemsetAsync(d_ws, 0, (size_t)N * 5 * sizeof(float), stream);

    const int nChunks = T / 64;
    int grid = nChunks < 4096 ? nChunks : 4096;
    triplet_mlp_kernel<<<grid, 256, 0, stream>>>(messages, r2, W1, b1, W2, b2, W3, b3,
                                                 idx_kj, sacc, cntp, nChunks);

    const int n4 = N * 4;
    finalize_kernel<<<(n4 + 255) / 256, 256, 0, stream>>>(sacc, cntp, (float*)d_out, n4);
}

// Round 7
// 299.232 us; speedup vs baseline: 2.0404x; 2.0404x over previous
//
#include <hip/hip_runtime.h>

// MFMA fragment types (gfx950): 16x16x32 f16 -> A/B = 8 x _Float16, C/D = 4 x float
typedef _Float16 half8 __attribute__((ext_vector_type(8)));
typedef __fp16 fp16x2 __attribute__((ext_vector_type(2)));   // cvt_pkrtz return type
typedef float floatx4 __attribute__((ext_vector_type(4)));
typedef unsigned int uintx4 __attribute__((ext_vector_type(4)));

#define MSGW 64      // message width
#define DEG 8        // fixed in-degree; triplets per edge

// log2-domain softplus: u = max(z',0) + log2(1+2^-|z'|) where z' = log2e*z.
// Then ln2*u = softplus(z). Scale factors folded into staged weights:
//   W1,b1 *= log2e  (so layer-1 acc is z1')
//   W2 unscaled, b2 *= log2e  (ln2*u1 @ W2 * log2e keeps the domain: ln2*log2e = 1)
//   W3 *= ln2 (recovers h2 @ W3 from u2)
__device__ __forceinline__ float softplus_l2(float z) {
    float e = __builtin_amdgcn_exp2f(-__builtin_fabsf(z));   // 2^-|z'|
    return fmaxf(z, 0.0f) + __builtin_amdgcn_logf(1.0f + e); // v_log_f32 = log2
}

__device__ __forceinline__ half8 cvt8(const float* p) {
    float4 x = *(const float4*)p;
    float4 y = *(const float4*)(p + 4);
    uintx4 w;
    w.x = __builtin_bit_cast(unsigned int, __builtin_amdgcn_cvt_pkrtz(x.x, x.y));
    w.y = __builtin_bit_cast(unsigned int, __builtin_amdgcn_cvt_pkrtz(x.z, x.w));
    w.z = __builtin_bit_cast(unsigned int, __builtin_amdgcn_cvt_pkrtz(y.x, y.y));
    w.w = __builtin_bit_cast(unsigned int, __builtin_amdgcn_cvt_pkrtz(y.z, y.w));
    return __builtin_bit_cast(half8, w);
}

// TRANSPOSED formulation: compute h^T = W^T @ X so that hidden units live on
// MFMA rows and triplets on columns. Lane (q = lane>>4, s = lane&15):
//   A-frag: A[m=s][k=q*8+j]    B-frag: B[k=q*8+j][n=s]    C/D: D[q*4+rr][s]
// The gathered message fragment (8 consecutive k of triplet s per lane) is
// simultaneously a valid B-fragment -> same gather as the untransposed form.
// Layer-2's K-order is OURS to choose (MFMA sums K in any order; we permute
// W2's staged A-fragment to match): k-slot (ks2,q,j) <- hidden
//   h = (ks2*2 + (j>>2))*16 + q*4 + (j&3)
// which makes each lane's layer-1 outputs exactly its own layer-2 B-fragment:
// ZERO inter-layer shuffles/LDS. Epilogue: each lane holds 16 hidden of its
// own triplet -> 2 shuffles (m reduce) + 3 shuffles (edge pool).
//
// LAUNCH_BOUNDS LESSON (R3/R5/R6): the compiler budgets VGPRs as
// 256/min_waves_per_EU (NOT 512/w): w=4 -> cap 64, w=6 -> cap 40 => massive
// scratch spill (500MB WRITE_SIZE). Declare w=3 (cap ~84, spill-free); actual
// HW occupancy is set by real usage: LDS 25.6KB -> 6 blocks/CU, VGPR<=85 -> 6.
__global__ __launch_bounds__(256, 3)
void triplet_mlp_kernel(const float* __restrict__ messages,
                        const float* __restrict__ r2,
                        const float* __restrict__ W1, const float* __restrict__ b1,
                        const float* __restrict__ W2, const float* __restrict__ b2,
                        const float* __restrict__ W3, const float* __restrict__ b3,
                        const int* __restrict__ idx_kj,
                        float* __restrict__ sacc, float* __restrict__ cnt,
                        int nChunks)
{
    __shared__ __align__(16) _Float16 lw1x[16 * 512];  // frag (nt*4+ks), lane-order, *log2e
    __shared__ __align__(16) _Float16 lw2x[8 * 512];   // frag (nt2*2+ks2), K-permuted
    __shared__ __align__(16) float lb1[64];            // *log2e
    __shared__ __align__(16) float lb2[64];            // *log2e
    __shared__ __align__(16) float lw3f[64];           // *ln2

    const float LOG2E = 1.44269504088896340736f;
    const float LN2   = 0.69314718055994530942f;

    const int tid = threadIdx.x;
    for (int i = tid; i < 128 * 64; i += 256) {
        int k = i >> 6, n = i & 63;          // W1[k][n] row-major
        int ks = k >> 5, q = (k >> 3) & 3, j = k & 7;
        int nt = n >> 4, s = n & 15;
        lw1x[(nt * 4 + ks) * 512 + (q * 16 + s) * 8 + j] = (_Float16)(W1[i] * LOG2E);
    }
    for (int i = tid; i < 64 * 64; i += 256) {
        int h = i >> 6, n = i & 63;          // W2[h][n] row-major
        int ks2 = h >> 5, q = (h >> 2) & 3, j = ((h >> 4) & 1) * 4 + (h & 3);
        int nt2 = n >> 4, s = n & 15;
        lw2x[(nt2 * 2 + ks2) * 512 + (q * 16 + s) * 8 + j] = (_Float16)W2[i];
    }
    if (tid < 64) {
        lb1[tid] = b1[tid] * LOG2E;
        lb2[tid] = b2[tid] * LOG2E;
        lw3f[tid] = W3[tid] * LN2;
    }
    __syncthreads();

    const int lane = tid & 63;
    const int s = lane & 15;                 // triplet column within the 16-wide tile
    const int q = lane >> 4;                 // quad
    const float b3v = b3[0];
    const int T = nChunks * 64;
    const int stride = gridDim.x * 64;

    int t = blockIdx.x * 64 + (tid >> 6) * 16 + s;   // this lane's triplet
    int kj = (t < T) ? idx_kj[t] : 0;

    for (int chunk = blockIdx.x; chunk < nChunks; chunk += gridDim.x) {
        // rotating index prefetch
        const int t_next = t + stride;
        const int kj_next = idx_kj[(t_next < T) ? t_next : 0];

        const int ji = t >> 3;                   // idx_ji[t] structural
        const int jn = kj >> 3;                  // idx_j[t] structural (uniform per edge)

        // gather B-fragments: k 0..63 = messages[kj], 64..127 = messages[ji]
        const float* mk = messages + (size_t)kj * MSGW + q * 8;
        const float* mj = messages + (size_t)ji * MSGW + q * 8;
        half8 bfr[4];
        bfr[0] = cvt8(mk);
        bfr[1] = cvt8(mk + 32);
        bfr[2] = cvt8(mj);
        bfr[3] = cvt8(mj + 32);

        const float rk = r2[(size_t)kj * 2 + (q & 1)];   // only this quad's component

        // ---- layer 1 (transposed): z1'^T[64x16] = (log2e*W1)^T @ X ----
        floatx4 acc[4];
#pragma unroll
        for (int nt = 0; nt < 4; ++nt)
            acc[nt] = *(const floatx4*)&lb1[nt * 16 + q * 4];   // broadcast b128
#pragma unroll
        for (int ks = 0; ks < 4; ++ks)
#pragma unroll
            for (int nt = 0; nt < 4; ++nt) {
                half8 af = *(const half8*)&lw1x[(nt * 4 + ks) * 512 + lane * 8];
                acc[nt] = __builtin_amdgcn_mfma_f32_16x16x32_f16(af, bfr[ks], acc[nt], 0, 0, 0);
            }

        // softplus (log2-domain) + pack: vector bit_casts, SROA-safe
        uintx4 w0, w1;
        w0.x = __builtin_bit_cast(unsigned int,
                __builtin_amdgcn_cvt_pkrtz(softplus_l2(acc[0][0]), softplus_l2(acc[0][1])));
        w0.y = __builtin_bit_cast(unsigned int,
                __builtin_amdgcn_cvt_pkrtz(softplus_l2(acc[0][2]), softplus_l2(acc[0][3])));
        w0.z = __builtin_bit_cast(unsigned int,
                __builtin_amdgcn_cvt_pkrtz(softplus_l2(acc[1][0]), softplus_l2(acc[1][1])));
        w0.w = __builtin_bit_cast(unsigned int,
                __builtin_amdgcn_cvt_pkrtz(softplus_l2(acc[1][2]), softplus_l2(acc[1][3])));
        w1.x = __builtin_bit_cast(unsigned int,
                __builtin_amdgcn_cvt_pkrtz(softplus_l2(acc[2][0]), softplus_l2(acc[2][1])));
        w1.y = __builtin_bit_cast(unsigned int,
                __builtin_amdgcn_cvt_pkrtz(softplus_l2(acc[2][2]), softplus_l2(acc[2][3])));
        w1.z = __builtin_bit_cast(unsigned int,
                __builtin_amdgcn_cvt_pkrtz(softplus_l2(acc[3][0]), softplus_l2(acc[3][1])));
        w1.w = __builtin_bit_cast(unsigned int,
                __builtin_amdgcn_cvt_pkrtz(softplus_l2(acc[3][2]), softplus_l2(acc[3][3])));
        half8 u1a = __builtin_bit_cast(half8, w0);   // layer-2 B-frag, ks2=0
        half8 u1b = __builtin_bit_cast(half8, w1);   // layer-2 B-frag, ks2=1

        // ---- layer 2 (transposed, K-permuted): z2'^T = W2^T @ u1^T ----
        floatx4 acc2[4];
#pragma unroll
        for (int nt2 = 0; nt2 < 4; ++nt2)
            acc2[nt2] = *(const floatx4*)&lb2[nt2 * 16 + q * 4];
#pragma unroll
        for (int nt2 = 0; nt2 < 4; ++nt2) {
            half8 af0 = *(const half8*)&lw2x[(nt2 * 2 + 0) * 512 + lane * 8];
            acc2[nt2] = __builtin_amdgcn_mfma_f32_16x16x32_f16(af0, u1a, acc2[nt2], 0, 0, 0);
            half8 af1 = *(const half8*)&lw2x[(nt2 * 2 + 1) * 512 + lane * 8];
            acc2[nt2] = __builtin_amdgcn_mfma_f32_16x16x32_f16(af1, u1b, acc2[nt2], 0, 0, 0);
        }

        // ---- layer 3: m[s] = sum_h softplus(z2)[h] * W3[h] + b3 ----
        float msum = 0.0f;
#pragma unroll
        for (int nt2 = 0; nt2 < 4; ++nt2) {
            floatx4 w3q = *(const floatx4*)&lw3f[nt2 * 16 + q * 4];
#pragma unroll
            for (int rr = 0; rr < 4; ++rr)
                msum += softplus_l2(acc2[nt2][rr]) * w3q[rr];
        }
        msum += __shfl_xor(msum, 16, 64);     // reduce over the 4 q-lanes of column s
        msum += __shfl_xor(msum, 32, 64);
        const float m = msum + b3v;

        // edge pooling: v[bb] = sum_{k in edge} m_k * rk_k[bb], bb = q&1
        float c = m * rk;
        c += __shfl_xor(c, 1, 16);
        c += __shfl_xor(c, 2, 16);
        c += __shfl_xor(c, 4, 16);            // lanes s=0/s=8 hold the two edges' sums

        if ((s & 7) == 0) {
            const int aa = q >> 1, bb = q & 1;           // dyad: rj[aa]*v[bb]
            const float rj = r2[(size_t)ji * 2 + aa];    // ji uniform within edge
            atomicAdd(&sacc[(size_t)jn * 4 + aa * 2 + bb], rj * c);
            if (q == 0) atomicAdd(&cnt[jn], 8.0f);       // 8 triplets pooled per edge
        }

        t = t_next;
        kj = kj_next;
    }
}

__global__ void finalize_kernel(const float* __restrict__ sacc, const float* __restrict__ cnt,
                                float* __restrict__ out, int n4) {
    int i = blockIdx.x * 256 + threadIdx.x;
    if (i < n4) {
        float c = cnt[i >> 2];
        out[i] = sacc[i] / fmaxf(c, 1.0f);
    }
}

extern "C" void kernel_launch(void* const* d_in, const int* in_sizes, int n_in,
                              void* d_out, int out_size, void* d_ws, size_t ws_size,
                              hipStream_t stream) {
    const float* messages = (const float*)d_in[0];
    const float* r2       = (const float*)d_in[1];
    const float* W1       = (const float*)d_in[2];
    const float* b1       = (const float*)d_in[3];
    const float* W2       = (const float*)d_in[4];
    const float* b2       = (const float*)d_in[5];
    const float* W3       = (const float*)d_in[6];
    const float* b3       = (const float*)d_in[7];
    const int* idx_kj     = (const int*)d_in[8];

    const int T = in_sizes[8];          // 1,280,000 triplets
    const int N = out_size / 4;         // 20,000 nodes
    float* sacc = (float*)d_ws;         // [N*4] pooled sums
    float* cntp = sacc + (size_t)N * 4; // [N] counts

    (void)hipMemsetAsync(d_ws, 0, (size_t)N * 5 * sizeof(float), stream);

    const int nChunks = T / 64;
    int grid = nChunks < 4096 ? nChunks : 4096;
    triplet_mlp_kernel<<<grid, 256, 0, stream>>>(messages, r2, W1, b1, W2, b2, W3, b3,
                                                 idx_kj, sacc, cntp, nChunks);

    const int n4 = N * 4;
    finalize_kernel<<<(n4 + 255) / 256, 256, 0, stream>>>(sacc, cntp, (float*)d_out, n4);
}

// Round 8
// 255.238 us; speedup vs baseline: 2.3921x; 1.1724x over previous
//
#include <hip/hip_runtime.h>

// MFMA fragment types (gfx950): 16x16x32 f16 -> A/B = 8 x _Float16, C/D = 4 x float
typedef _Float16 half8 __attribute__((ext_vector_type(8)));
typedef __fp16 fp16x2 __attribute__((ext_vector_type(2)));   // cvt_pkrtz return type
typedef float floatx4 __attribute__((ext_vector_type(4)));
typedef unsigned int uintx4 __attribute__((ext_vector_type(4)));

#define MSGW 64      // message width
#define DEG 8        // fixed in-degree; triplets per edge

// log2-domain softplus: u = max(z',0) + log2(1+2^-|z'|) where z' = log2e*z.
// Then ln2*u = softplus(z). Scale factors folded into staged weights:
//   W1,b1 *= log2e  (so layer-1 acc is z1')
//   W2 unscaled, b2 *= log2e  (ln2*u1 @ W2 * log2e keeps the domain: ln2*log2e = 1)
//   W3 *= ln2 (recovers h2 @ W3 from u2)
__device__ __forceinline__ float softplus_l2(float z) {
    float e = __builtin_amdgcn_exp2f(-__builtin_fabsf(z));   // 2^-|z'|
    return fmaxf(z, 0.0f) + __builtin_amdgcn_logf(1.0f + e); // v_log_f32 = log2
}

__device__ __forceinline__ half8 cvt8(const float* p) {
    float4 x = *(const float4*)p;
    float4 y = *(const float4*)(p + 4);
    uintx4 w;
    w.x = __builtin_bit_cast(unsigned int, __builtin_amdgcn_cvt_pkrtz(x.x, x.y));
    w.y = __builtin_bit_cast(unsigned int, __builtin_amdgcn_cvt_pkrtz(x.z, x.w));
    w.z = __builtin_bit_cast(unsigned int, __builtin_amdgcn_cvt_pkrtz(y.x, y.y));
    w.w = __builtin_bit_cast(unsigned int, __builtin_amdgcn_cvt_pkrtz(y.z, y.w));
    return __builtin_bit_cast(half8, w);
}

// TRANSPOSED formulation: compute h^T = W^T @ X so that hidden units live on
// MFMA rows and triplets on columns. Lane (q = lane>>4, s = lane&15):
//   A-frag: A[m=s][k=q*8+j]    B-frag: B[k=q*8+j][n=s]    C/D: D[q*4+rr][s]
// The gathered message fragment (8 consecutive k of triplet s per lane) is
// simultaneously a valid B-fragment -> same gather as the untransposed form.
// Layer-2's K-order is OURS to choose (MFMA sums K in any order; we permute
// W2's staged A-fragment to match): k-slot (ks2,q,j) <- hidden
//   h = (ks2*2 + (j>>2))*16 + q*4 + (j&3)
// which makes each lane's layer-1 outputs exactly its own layer-2 B-fragment:
// ZERO inter-layer shuffles/LDS. Epilogue: each lane holds 16 hidden of its
// own triplet -> 2 shuffles (m reduce) + 3 shuffles (edge pool).
//
// LAUNCH_BOUNDS LESSON (R3/R5/R6/R7): compiler VGPR budget = 256/min_waves_per_EU
// (w=3 -> 84, w=4 -> 64, w=6 -> 40). This kernel's natural pressure is ~90-100;
// ANY cap below that spills to scratch (R7: 240MB extra HBM, slower than a
// lower-occupancy spill-free build). Use w=2 (cap 128): spill-free at ~95 VGPR;
// HW occupancy = min(VGPR<=128 -> 4 blk, LDS 25.6KB -> 6 blk) = 4 blocks/CU.
__global__ __launch_bounds__(256, 2)
void triplet_mlp_kernel(const float* __restrict__ messages,
                        const float* __restrict__ r2,
                        const float* __restrict__ W1, const float* __restrict__ b1,
                        const float* __restrict__ W2, const float* __restrict__ b2,
                        const float* __restrict__ W3, const float* __restrict__ b3,
                        const int* __restrict__ idx_kj,
                        float* __restrict__ sacc, float* __restrict__ cnt,
                        int nChunks)
{
    __shared__ __align__(16) _Float16 lw1x[16 * 512];  // frag (nt*4+ks), lane-order, *log2e
    __shared__ __align__(16) _Float16 lw2x[8 * 512];   // frag (nt2*2+ks2), K-permuted
    __shared__ __align__(16) float lb1[64];            // *log2e
    __shared__ __align__(16) float lb2[64];            // *log2e
    __shared__ __align__(16) float lw3f[64];           // *ln2

    const float LOG2E = 1.44269504088896340736f;
    const float LN2   = 0.69314718055994530942f;

    const int tid = threadIdx.x;
    for (int i = tid; i < 128 * 64; i += 256) {
        int k = i >> 6, n = i & 63;          // W1[k][n] row-major
        int ks = k >> 5, q = (k >> 3) & 3, j = k & 7;
        int nt = n >> 4, s = n & 15;
        lw1x[(nt * 4 + ks) * 512 + (q * 16 + s) * 8 + j] = (_Float16)(W1[i] * LOG2E);
    }
    for (int i = tid; i < 64 * 64; i += 256) {
        int h = i >> 6, n = i & 63;          // W2[h][n] row-major
        int ks2 = h >> 5, q = (h >> 2) & 3, j = ((h >> 4) & 1) * 4 + (h & 3);
        int nt2 = n >> 4, s = n & 15;
        lw2x[(nt2 * 2 + ks2) * 512 + (q * 16 + s) * 8 + j] = (_Float16)W2[i];
    }
    if (tid < 64) {
        lb1[tid] = b1[tid] * LOG2E;
        lb2[tid] = b2[tid] * LOG2E;
        lw3f[tid] = W3[tid] * LN2;
    }
    __syncthreads();

    const int lane = tid & 63;
    const int s = lane & 15;                 // triplet column within the 16-wide tile
    const int q = lane >> 4;                 // quad
    const float b3v = b3[0];
    const int T = nChunks * 64;
    const int stride = gridDim.x * 64;

    int t = blockIdx.x * 64 + (tid >> 6) * 16 + s;   // this lane's triplet
    int kj = (t < T) ? idx_kj[t] : 0;

    for (int chunk = blockIdx.x; chunk < nChunks; chunk += gridDim.x) {
        // rotating index prefetch
        const int t_next = t + stride;
        const int kj_next = idx_kj[(t_next < T) ? t_next : 0];

        const int ji = t >> 3;                   // idx_ji[t] structural
        const int jn = kj >> 3;                  // idx_j[t] structural (uniform per edge)

        // gather B-fragments: k 0..63 = messages[kj], 64..127 = messages[ji]
        const float* mk = messages + (size_t)kj * MSGW + q * 8;
        const float* mj = messages + (size_t)ji * MSGW + q * 8;
        half8 bfr[4];
        bfr[0] = cvt8(mk);
        bfr[1] = cvt8(mk + 32);
        bfr[2] = cvt8(mj);
        bfr[3] = cvt8(mj + 32);

        const float rk = r2[(size_t)kj * 2 + (q & 1)];   // only this quad's component

        // ---- layer 1 (transposed): z1'^T[64x16] = (log2e*W1)^T @ X ----
        floatx4 acc[4];
#pragma unroll
        for (int nt = 0; nt < 4; ++nt)
            acc[nt] = *(const floatx4*)&lb1[nt * 16 + q * 4];   // broadcast b128
#pragma unroll
        for (int ks = 0; ks < 4; ++ks)
#pragma unroll
            for (int nt = 0; nt < 4; ++nt) {
                half8 af = *(const half8*)&lw1x[(nt * 4 + ks) * 512 + lane * 8];
                acc[nt] = __builtin_amdgcn_mfma_f32_16x16x32_f16(af, bfr[ks], acc[nt], 0, 0, 0);
            }

        // softplus (log2-domain) + pack: vector bit_casts, SROA-safe
        uintx4 w0, w1;
        w0.x = __builtin_bit_cast(unsigned int,
                __builtin_amdgcn_cvt_pkrtz(softplus_l2(acc[0][0]), softplus_l2(acc[0][1])));
        w0.y = __builtin_bit_cast(unsigned int,
                __builtin_amdgcn_cvt_pkrtz(softplus_l2(acc[0][2]), softplus_l2(acc[0][3])));
        w0.z = __builtin_bit_cast(unsigned int,
                __builtin_amdgcn_cvt_pkrtz(softplus_l2(acc[1][0]), softplus_l2(acc[1][1])));
        w0.w = __builtin_bit_cast(unsigned int,
                __builtin_amdgcn_cvt_pkrtz(softplus_l2(acc[1][2]), softplus_l2(acc[1][3])));
        w1.x = __builtin_bit_cast(unsigned int,
                __builtin_amdgcn_cvt_pkrtz(softplus_l2(acc[2][0]), softplus_l2(acc[2][1])));
        w1.y = __builtin_bit_cast(unsigned int,
                __builtin_amdgcn_cvt_pkrtz(softplus_l2(acc[2][2]), softplus_l2(acc[2][3])));
        w1.z = __builtin_bit_cast(unsigned int,
                __builtin_amdgcn_cvt_pkrtz(softplus_l2(acc[3][0]), softplus_l2(acc[3][1])));
        w1.w = __builtin_bit_cast(unsigned int,
                __builtin_amdgcn_cvt_pkrtz(softplus_l2(acc[3][2]), softplus_l2(acc[3][3])));
        half8 u1a = __builtin_bit_cast(half8, w0);   // layer-2 B-frag, ks2=0
        half8 u1b = __builtin_bit_cast(half8, w1);   // layer-2 B-frag, ks2=1

        // ---- layer 2 (transposed, K-permuted): z2'^T = W2^T @ u1^T ----
        floatx4 acc2[4];
#pragma unroll
        for (int nt2 = 0; nt2 < 4; ++nt2)
            acc2[nt2] = *(const floatx4*)&lb2[nt2 * 16 + q * 4];
#pragma unroll
        for (int nt2 = 0; nt2 < 4; ++nt2) {
            half8 af0 = *(const half8*)&lw2x[(nt2 * 2 + 0) * 512 + lane * 8];
            acc2[nt2] = __builtin_amdgcn_mfma_f32_16x16x32_f16(af0, u1a, acc2[nt2], 0, 0, 0);
            half8 af1 = *(const half8*)&lw2x[(nt2 * 2 + 1) * 512 + lane * 8];
            acc2[nt2] = __builtin_amdgcn_mfma_f32_16x16x32_f16(af1, u1b, acc2[nt2], 0, 0, 0);
        }

        // ---- layer 3: m[s] = sum_h softplus(z2)[h] * W3[h] + b3 ----
        float msum = 0.0f;
#pragma unroll
        for (int nt2 = 0; nt2 < 4; ++nt2) {
            floatx4 w3q = *(const floatx4*)&lw3f[nt2 * 16 + q * 4];
#pragma unroll
            for (int rr = 0; rr < 4; ++rr)
                msum += softplus_l2(acc2[nt2][rr]) * w3q[rr];
        }
        msum += __shfl_xor(msum, 16, 64);     // reduce over the 4 q-lanes of column s
        msum += __shfl_xor(msum, 32, 64);
        const float m = msum + b3v;

        // edge pooling: v[bb] = sum_{k in edge} m_k * rk_k[bb], bb = q&1
        float c = m * rk;
        c += __shfl_xor(c, 1, 16);
        c += __shfl_xor(c, 2, 16);
        c += __shfl_xor(c, 4, 16);            // lanes s=0/s=8 hold the two edges' sums

        if ((s & 7) == 0) {
            const int aa = q >> 1, bb = q & 1;           // dyad: rj[aa]*v[bb]
            const float rj = r2[(size_t)ji * 2 + aa];    // ji uniform within edge
            atomicAdd(&sacc[(size_t)jn * 4 + aa * 2 + bb], rj * c);
            if (q == 0) atomicAdd(&cnt[jn], 8.0f);       // 8 triplets pooled per edge
        }

        t = t_next;
        kj = kj_next;
    }
}

__global__ void finalize_kernel(const float* __restrict__ sacc, const float* __restrict__ cnt,
                                float* __restrict__ out, int n4) {
    int i = blockIdx.x * 256 + threadIdx.x;
    if (i < n4) {
        float c = cnt[i >> 2];
        out[i] = sacc[i] / fmaxf(c, 1.0f);
    }
}

extern "C" void kernel_launch(void* const* d_in, const int* in_sizes, int n_in,
                              void* d_out, int out_size, void* d_ws, size_t ws_size,
                              hipStream_t stream) {
    const float* messages = (const float*)d_in[0];
    const float* r2       = (const float*)d_in[1];
    const float* W1       = (const float*)d_in[2];
    const float* b1       = (const float*)d_in[3];
    const float* W2       = (const float*)d_in[4];
    const float* b2       = (const float*)d_in[5];
    const float* W3       = (const float*)d_in[6];
    const float* b3       = (const float*)d_in[7];
    const int* idx_kj     = (const int*)d_in[8];

    const int T = in_sizes[8];          // 1,280,000 triplets
    const int N = out_size / 4;         // 20,000 nodes
    float* sacc = (float*)d_ws;         // [N*4] pooled sums
    float* cntp = sacc + (size_t)N * 4; // [N] counts

    (void)hipMemsetAsync(d_ws, 0, (size_t)N * 5 * sizeof(float), stream);

    const int nChunks = T / 64;
    int grid = nChunks < 4096 ? nChunks : 4096;
    triplet_mlp_kernel<<<grid, 256, 0, stream>>>(messages, r2, W1, b1, W2, b2, W3, b3,
                                                 idx_kj, sacc, cntp, nChunks);

    const int n4 = N * 4;
    finalize_kernel<<<(n4 + 255) / 256, 256, 0, stream>>>(sacc, cntp, (float*)d_out, n4);
}